// Round 7
// baseline (40.441 us; speedup 1.0000x reference)
//
#include <hip/hip_runtime.h>
#include <hip/hip_fp16.h>

#define HW 196
#define C  384
#define CF4 (C/4)          // 96 float4 per row
#define TK 98
#define NT 1024
#define NWAVE (NT/64)      // 16

__global__ __launch_bounds__(NT, 4) void sampling_kernel(
    const float* __restrict__ token,
    const float* __restrict__ feature,
    float* __restrict__ out)
{
    // 147 KB fp16 stage of this pair's full feature tile -> pass 2 never
    // touches global memory again. 1 block/CU (LDS-bound), 16 waves.
    __shared__ __half feat16[HW][C];
    __shared__ float tokLds[C];
    __shared__ float score[HW];
    __shared__ float selW[TK];
    __shared__ int   selIdx[TK];
    __shared__ float wsum[NWAVE];
    __shared__ int   rank2[2 * HW];
    __shared__ float part2[2][C];
    __shared__ float s_max, s_winv;

    const int tid  = threadIdx.x;
    const int wave = tid >> 6;
    const int lane = tid & 63;
    const int l8   = lane & 7;         // sub-lane within 8-lane group
    const int g8   = lane >> 3;        // group 0..7 within wave
    const int pair = blockIdx.x;

    const float* tokp  = token   + (size_t)pair * C;
    const float* featp = feature + (size_t)pair * (HW * C);
    const float4* f4base = (const float4*)featp;
    const float4* t4     = (const float4*)tokLds;

    // stage token row (384 f32) in LDS
    for (int i = tid; i < C; i += NT) tokLds[i] = tokp[i];
    __syncthreads();

    // this lane's token column-slice in registers: cols l8*4+32k
    float4 tok[12];
    #pragma unroll
    for (int k = 0; k < 12; ++k) tok[k] = t4[l8 + 8 * k];

    const float scale = 0.05103103630798288f;  // 384^-0.5

    // ---- pass 1: 8-lane group per row, 128 groups -> 2 iters.
    // Each lane: 12 independent float4 loads (128B-contiguous per group),
    // score FMA against register token, fp16 stage into LDS. ----
    #pragma unroll
    for (int it = 0; it < 2; ++it) {
        const int r = it * 128 + wave * 8 + g8;
        if (r < HW) {
            const float4* fr = f4base + (size_t)r * CF4 + l8;
            float4 a[12];
            #pragma unroll
            for (int k = 0; k < 12; ++k) a[k] = fr[8 * k];
            float4 acc = make_float4(0.f, 0.f, 0.f, 0.f);
            #pragma unroll
            for (int k = 0; k < 12; ++k) {
                acc.x += a[k].x * tok[k].x; acc.y += a[k].y * tok[k].y;
                acc.z += a[k].z * tok[k].z; acc.w += a[k].w * tok[k].w;
            }
            #pragma unroll
            for (int k = 0; k < 12; ++k) {
                const int c0 = l8 * 4 + 32 * k;
                *(__half2*)&feat16[r][c0]     = __floats2half2_rn(a[k].x, a[k].y);
                *(__half2*)&feat16[r][c0 + 2] = __floats2half2_rn(a[k].z, a[k].w);
            }
            float s = (acc.x + acc.y) + (acc.z + acc.w);
            s += __shfl_xor(s, 1, 64);
            s += __shfl_xor(s, 2, 64);
            s += __shfl_xor(s, 4, 64);
            if (l8 == 0) score[r] = s * scale;
        }
    }
    __syncthreads();

    // ---- concurrent: threads 0..391 rank-count (half-range each);
    //      last wave computes the max. ----
    if (tid < 2 * HW) {
        const int i = tid >> 1, h = tid & 1;
        const float si = score[i];
        int cnt = 0;
        const int j0 = h * (HW / 2);
        for (int j = j0; j < j0 + HW / 2; ++j) {
            const float sj = score[j];
            cnt += (int)((sj > si) | ((sj == si) & (j < i)));
        }
        rank2[tid] = cnt;
    } else if (wave == NWAVE - 1) {
        float m = -3.4e38f;
        for (int i = lane; i < HW; i += 64) m = fmaxf(m, score[i]);
        #pragma unroll
        for (int off = 32; off > 0; off >>= 1)
            m = fmaxf(m, __shfl_xor(m, off, 64));
        if (lane == 0) s_max = m;
    }
    __syncthreads();

    // ---- select + compact (softmax denom cancels: w = exp(s - max)) ----
    float w = 0.f;
    if (tid < HW) {
        const int rank = rank2[2 * tid] + rank2[2 * tid + 1];
        if (rank < TK) {
            w = __expf(score[tid] - s_max);
            selIdx[rank] = tid;
            selW[rank]  = w;
        }
    }
    #pragma unroll
    for (int off = 32; off > 0; off >>= 1) w += __shfl_xor(w, off, 64);
    if (lane == 0) wsum[wave] = w;
    __syncthreads();
    if (tid == 0) {
        float s = 0.f;
        #pragma unroll
        for (int i = 0; i < NWAVE; ++i) s += wsum[i];
        s_winv = 1.f / s;
    }
    __syncthreads();

    // ---- pass 2: weighted sum entirely from LDS (fp16).
    // 768 threads: h = row-parity, c = channel; 49 rows each. ----
    if (tid < 2 * C) {
        const int h = tid >> 8 >= 1 ? (tid >= C ? 1 : 0) : 0; // h = tid/C
        const int hh = (tid >= C) ? 1 : 0;
        const int c  = tid - hh * C;
        float acc = 0.f;
        #pragma unroll 7
        for (int i = hh; i < TK; i += 2)
            acc += selW[i] * __half2float(feat16[selIdx[i]][c]);
        part2[hh][c] = acc;
        (void)h;
    }
    __syncthreads();

    if (tid < C)
        out[(size_t)pair * C + tid] = (part2[0][tid] + part2[1][tid]) * s_winv;
}

extern "C" void kernel_launch(void* const* d_in, const int* in_sizes, int n_in,
                              void* d_out, int out_size, void* d_ws, size_t ws_size,
                              hipStream_t stream) {
    const float* token   = (const float*)d_in[0];
    const float* feature = (const float*)d_in[1];
    float* out = (float*)d_out;
    const int pairs = in_sizes[0] / C;   // 8*16*4 = 512
    sampling_kernel<<<pairs, NT, 0, stream>>>(token, feature, out);
}